// Round 6
// baseline (298.564 us; speedup 1.0000x reference)
//
#include <hip/hip_runtime.h>
#include <math.h>
#include <stdint.h>

#define C        128
#define KCODES   1024
#define TPB      256
#define ROWS_PB  64
#define NCHUNK   32                  // codes per partition per chunk
#define NCHUNKS  16                  // 512 / 32
#define BSTRIDE  272                 // padded LDS row stride (bytes): 256 + 16
#define PARTB    (NCHUNK * BSTRIDE)  // 8704
#define BUFB     (2 * PARTB)         // 17408 (two partitions)
#define EPS_TRIG 1.0f

typedef __attribute__((ext_vector_type(8))) short bf16x8_t;
typedef __attribute__((ext_vector_type(4))) float f32x4_t;
#define MFMA_BF16 __builtin_amdgcn_mfma_f32_16x16x32_bf16

static __device__ __forceinline__ uint32_t bf16_rne(float f) {
    uint32_t u = __float_as_uint(f);
    return (u + 0x7FFFu + ((u >> 16) & 1u)) >> 16;
}

// sorted lex insert into top-3 (value, then code index) — epilogue/merge only
static __device__ __forceinline__ void ins3(float v, int k, float* q, int* ki) {
    bool b0 = (v < q[0]) || (v == q[0] && k < ki[0]);
    bool b1 = (v < q[1]) || (v == q[1] && k < ki[1]);
    bool b2 = (v < q[2]) || (v == q[2] && k < ki[2]);
    q[2]  = b1 ? q[1]  : (b2 ? v : q[2]);   ki[2] = b1 ? ki[1] : (b2 ? k : ki[2]);
    q[1]  = b0 ? q[0]  : (b1 ? v : q[1]);   ki[1] = b0 ? ki[0] : (b1 ? k : ki[1]);
    q[0]  = b0 ? v     : q[0];              ki[0] = b0 ? k     : ki[0];
}

// ---------------- prep: bf16(codebook) + ||c||^2 in one kernel ----------------
__global__ void cb_prep_kernel(const float* __restrict__ cb,
                               uint16_t* __restrict__ cbh,
                               float* __restrict__ cq) {
    int k = blockIdx.x * blockDim.x + threadIdx.x;
    if (k >= KCODES) return;
    const float4* cp = (const float4*)(cb + (size_t)k * C);
    uint32_t* hp = (uint32_t*)(cbh + (size_t)k * C);
    float sx = 0.f, sy = 0.f, sz = 0.f, sw = 0.f;
    #pragma unroll
    for (int i = 0; i < C / 4; ++i) {
        float4 v = cp[i];
        sx += v.x * v.x; sy += v.y * v.y;
        sz += v.z * v.z; sw += v.w * v.w;
        hp[2 * i]     = bf16_rne(v.x) | (bf16_rne(v.y) << 16);
        hp[2 * i + 1] = bf16_rne(v.z) | (bf16_rne(v.w) << 16);
    }
    cq[k] = (sx + sy) + (sz + sw);   // R1 arithmetic order
}

// ---------------- main: 64 rows x 1024 codes per block ----------------
// 4 waves: (row-wave 0/1 = 32 rows) x (code-partition 0/1 = 512 codes).
// Single-bf16 MFMA scoring; exact fp32 top-3 per lane-slot with explicit
// index registers; 16-lane butterfly merge; fp64 re-decide within EPS band.
__global__ __launch_bounds__(TPB, 3)
void vq_mfma4_kernel(const float* __restrict__ x,
                     const float* __restrict__ cb,
                     const uint16_t* __restrict__ cbh,
                     const float* __restrict__ cq,
                     float* __restrict__ out_codes,
                     float* __restrict__ out_fidx,
                     float* __restrict__ out_idx,
                     float* __restrict__ out_dist,
                     int rows)
{
    __shared__ __align__(16) uint8_t s_buf[2 * BUFB];   // 34816 B double-buffered
    __shared__ float s_cq[2][2][NCHUNK];                 // [buf][part][code]
    __shared__ float s_rv[2][ROWS_PB][3];
    __shared__ int   s_rk[2][ROWS_PB][3];
    __shared__ int   s_kf[ROWS_PB];

    const int t    = threadIdx.x;
    const int lane = t & 63;
    const int w    = t >> 6;
    const int part = w >> 1;        // code partition 0/1
    const int rw   = w & 1;         // row-wave 0/1
    const int ln   = lane & 15;
    const int quad = lane >> 4;
    const int rowblock = blockIdx.x * ROWS_PB;

    // ---- A fragments (bf16 hi only) straight from global ----
    bf16x8_t ah[2][4];
    #pragma unroll
    for (int g = 0; g < 2; ++g) {
        int rowg = rowblock + rw * 32 + g * 16 + ln;
        rowg = rowg < rows ? rowg : rows - 1;
        const float* xp = x + (size_t)rowg * C + quad * 8;
        #pragma unroll
        for (int kk = 0; kk < 4; ++kk) {
            float4 v0 = *(const float4*)(xp + kk * 32);
            float4 v1 = *(const float4*)(xp + kk * 32 + 4);
            bf16x8_t hv;
            hv[0] = (short)bf16_rne(v0.x); hv[1] = (short)bf16_rne(v0.y);
            hv[2] = (short)bf16_rne(v0.z); hv[3] = (short)bf16_rne(v0.w);
            hv[4] = (short)bf16_rne(v1.x); hv[5] = (short)bf16_rne(v1.y);
            hv[6] = (short)bf16_rne(v1.z); hv[7] = (short)bf16_rne(v1.w);
            ah[g][kk] = hv;
        }
    }

    // ---- prologue: stage chunk 0 into buffer 0 ----
    uint4 ld[4];
    float pcq = 0.f;
    #pragma unroll
    for (int i = 0; i < 4; ++i) {
        int u = t + i * TPB;
        int pt = u >> 9, code = (u >> 4) & 31, gq = u & 15;
        ld[i] = ((const uint4*)cbh)[(((size_t)(pt * 512 + code)) << 4) + gq];
    }
    if (t < 64) pcq = cq[(t >> 5) * 512 + (t & 31)];
    #pragma unroll
    for (int i = 0; i < 4; ++i) {
        int u = t + i * TPB;
        int pt = u >> 9, code = (u >> 4) & 31, gq = u & 15;
        *(uint4*)(s_buf + pt * PARTB + code * BSTRIDE + gq * 16) = ld[i];
    }
    if (t < 64) s_cq[0][t >> 5][t & 31] = pcq;
    __syncthreads();

    // ---- exact fp32 top-3 per (rowgroup, acc-reg) slot ----
    float q[2][4][3];
    int   ki[2][4][3];
    #pragma unroll
    for (int g = 0; g < 2; ++g)
        #pragma unroll
        for (int r = 0; r < 4; ++r)
            #pragma unroll
            for (int j = 0; j < 3; ++j) { q[g][r][j] = INFINITY; ki[g][r][j] = 0x7fffffff; }

    #pragma unroll 1
    for (int chn = 0; chn < NCHUNKS; ++chn) {
        const int buf = chn & 1;
        // prefetch next chunk into registers
        if (chn + 1 < NCHUNKS) {
            const int kb2 = (chn + 1) * NCHUNK;
            #pragma unroll
            for (int i = 0; i < 4; ++i) {
                int u = t + i * TPB;
                int pt = u >> 9, code = (u >> 4) & 31, gq = u & 15;
                ld[i] = ((const uint4*)cbh)[(((size_t)(pt * 512 + kb2 + code)) << 4) + gq];
            }
            if (t < 64) pcq = cq[(t >> 5) * 512 + kb2 + (t & 31)];
        }

        // compute this chunk (wave's own partition: 32 codes = 2 ct-tiles)
        const uint8_t* bb = s_buf + buf * BUFB + part * PARTB + (size_t)ln * BSTRIDE + quad * 16;
        #pragma unroll
        for (int ct = 0; ct < 2; ++ct) {
            const uint8_t* bp = bb + (size_t)ct * 16 * BSTRIDE;
            f32x4_t acc0 = {0.f, 0.f, 0.f, 0.f};
            f32x4_t acc1 = {0.f, 0.f, 0.f, 0.f};
            #pragma unroll
            for (int kk = 0; kk < 4; ++kk) {
                bf16x8_t bh = *(const bf16x8_t*)(bp + kk * 64);
                acc0 = MFMA_BF16(ah[0][kk], bh, acc0, 0, 0, 0);
                acc1 = MFMA_BF16(ah[1][kk], bh, acc1, 0, 0, 0);
            }
            const float cqv = s_cq[buf][part][ct * 16 + ln];
            const int   kc  = part * 512 + chn * NCHUNK + ct * 16 + ln;
            #pragma unroll
            for (int g = 0; g < 2; ++g)
                #pragma unroll
                for (int r = 0; r < 4; ++r) {
                    float s_ = fmaf(-2.f, (g ? acc1 : acc0)[r], cqv);
                    bool b0 = s_ < q[g][r][0];
                    bool b1 = s_ < q[g][r][1];
                    bool b2 = s_ < q[g][r][2];
                    q[g][r][2]  = b1 ? q[g][r][1]  : (b2 ? s_ : q[g][r][2]);
                    ki[g][r][2] = b1 ? ki[g][r][1] : (b2 ? kc : ki[g][r][2]);
                    q[g][r][1]  = b0 ? q[g][r][0]  : (b1 ? s_ : q[g][r][1]);
                    ki[g][r][1] = b0 ? ki[g][r][0] : (b1 ? kc : ki[g][r][1]);
                    q[g][r][0]  = b0 ? s_ : q[g][r][0];
                    ki[g][r][0] = b0 ? kc : ki[g][r][0];
                }
        }

        // store prefetched chunk into the other buffer
        if (chn + 1 < NCHUNKS) {
            uint8_t* dst = s_buf + (1 - buf) * BUFB;
            #pragma unroll
            for (int i = 0; i < 4; ++i) {
                int u = t + i * TPB;
                int pt = u >> 9, code = (u >> 4) & 31, gq = u & 15;
                *(uint4*)(dst + pt * PARTB + code * BSTRIDE + gq * 16) = ld[i];
            }
            if (t < 64) s_cq[1 - buf][t >> 5][t & 31] = pcq;
        }
        __syncthreads();
    }

    // ---- butterfly top-3 merge across the 16 lanes of each col-group ----
    #pragma unroll
    for (int m = 1; m <= 8; m <<= 1) {
        #pragma unroll
        for (int g = 0; g < 2; ++g)
            #pragma unroll
            for (int r = 0; r < 4; ++r) {
                float ov0 = __shfl_xor(q[g][r][0], m, 16); int ok0 = __shfl_xor(ki[g][r][0], m, 16);
                float ov1 = __shfl_xor(q[g][r][1], m, 16); int ok1 = __shfl_xor(ki[g][r][1], m, 16);
                float ov2 = __shfl_xor(q[g][r][2], m, 16); int ok2 = __shfl_xor(ki[g][r][2], m, 16);
                ins3(ov0, ok0, q[g][r], ki[g][r]);
                ins3(ov1, ok1, q[g][r], ki[g][r]);
                ins3(ov2, ok2, q[g][r], ki[g][r]);
            }
    }
    if (ln == 0) {
        #pragma unroll
        for (int g = 0; g < 2; ++g)
            #pragma unroll
            for (int r = 0; r < 4; ++r) {
                int row_local = rw * 32 + g * 16 + quad * 4 + r;
                #pragma unroll
                for (int j = 0; j < 3; ++j) {
                    s_rv[part][row_local][j] = q[g][r][j];
                    s_rk[part][row_local][j] = ki[g][r][j];
                }
            }
    }
    __syncthreads();

    // ---- per-row finalize ----
    if (t < ROWS_PB) {
        int rowg = rowblock + t;
        bool valid = rowg < rows;
        int rowc = valid ? rowg : rows - 1;

        float cv[6]; int ck[6];
        #pragma unroll
        for (int p = 0; p < 2; ++p)
            #pragma unroll
            for (int j = 0; j < 3; ++j) { cv[p * 3 + j] = s_rv[p][t][j]; ck[p * 3 + j] = s_rk[p][t][j]; }

        int ib = 0;
        #pragma unroll
        for (int i = 1; i < 6; ++i)
            if (cv[i] < cv[ib] || (cv[i] == cv[ib] && ck[i] < ck[ib])) ib = i;
        const float v1 = cv[ib];
        int kfin = ck[ib];

        bool need = false;
        #pragma unroll
        for (int i = 0; i < 6; ++i)
            if (i != ib && cv[i] - v1 < EPS_TRIG) need = true;

        const float* xr = x + (size_t)rowc * C;
        // rs in R1 float4 order
        float sx = 0.f, sy = 0.f, sz = 0.f, sw = 0.f;
        {
            const float4* xp = (const float4*)xr;
            #pragma unroll
            for (int i = 0; i < C / 4; ++i) {
                float4 v = xp[i];
                sx += v.x * v.x; sy += v.y * v.y;
                sz += v.z * v.z; sw += v.w * v.w;
            }
        }
        const float rs = (sx + sy) + (sz + sw);

        float d;
        if (!need) {
            // exact fp32 distance, R1 chain order
            const float* cp = cb + (size_t)kfin * C;
            float a = 0.f;
            #pragma unroll 16
            for (int cc = 0; cc < C; ++cc) a = fmaf(xr[cc], cp[cc], a);
            d = (rs + cq[kfin]) - 2.f * a;
        } else {
            // fp64 re-decide among all candidates within the band
            double best = 1e300; int bestk = 0x7fffffff;
            #pragma unroll 1
            for (int i = 0; i < 6; ++i) {
                if (cv[i] - v1 < EPS_TRIG) {
                    const float* cp = cb + (size_t)ck[i] * C;
                    double dot = 0.0, cqq = 0.0;
                    #pragma unroll 8
                    for (int cc = 0; cc < C; ++cc) {
                        double xv = (double)xr[cc], cvv = (double)cp[cc];
                        dot += xv * cvv; cqq += cvv * cvv;
                    }
                    double qd = cqq - 2.0 * dot;
                    if (qd < best || (qd == best && ck[i] < bestk)) { best = qd; bestk = ck[i]; }
                }
            }
            kfin = bestk;
            d = (float)((double)rs + best);
        }

        if (valid) {
            out_fidx[rowg] = (float)kfin;
            out_idx[rowg]  = (float)kfin;
            out_dist[rowg] = d;
        }
        s_kf[t] = kfin;
    }
    __syncthreads();

    // ---- gather codes: 8 rows per iteration, 32 threads per row ----
    #pragma unroll 1
    for (int rr = 0; rr < ROWS_PB; rr += 8) {
        int r = rr + (t >> 5);
        int rowg2 = rowblock + r;
        if (rowg2 < rows) {
            const float4* src = (const float4*)(cb + (size_t)s_kf[r] * C);
            float4* dst = (float4*)(out_codes + (size_t)rowg2 * C);
            dst[t & 31] = src[t & 31];
        }
    }
}

// ---------------- fallback (R1 kernel, needs no workspace) ----------------
__global__ __launch_bounds__(TPB, 1)
void vq_nearest_fallback(const float* __restrict__ x,
                         const float* __restrict__ cb,
                         float* __restrict__ out_codes,
                         float* __restrict__ out_fidx,
                         float* __restrict__ out_idx,
                         float* __restrict__ out_dist,
                         int rows)
{
    __shared__ float s_cbsq[KCODES];
    const int t = threadIdx.x;
    for (int k = t; k < KCODES; k += TPB) {
        const float4* cp = (const float4*)(cb + (size_t)k * C);
        float sx = 0.f, sy = 0.f, sz = 0.f, sw = 0.f;
        #pragma unroll
        for (int i = 0; i < C / 4; ++i) {
            float4 v = cp[i];
            sx += v.x * v.x; sy += v.y * v.y; sz += v.z * v.z; sw += v.w * v.w;
        }
        s_cbsq[k] = (sx + sy) + (sz + sw);
    }
    __syncthreads();
    const int row = blockIdx.x * TPB + t;
    if (row >= rows) return;
    float xr[C];
    {
        const float4* xp = (const float4*)(x + (size_t)row * C);
        #pragma unroll
        for (int i = 0; i < C / 4; ++i) {
            float4 v = xp[i];
            xr[4*i+0] = v.x; xr[4*i+1] = v.y; xr[4*i+2] = v.z; xr[4*i+3] = v.w;
        }
    }
    float rs;
    {
        float sx = 0.f, sy = 0.f, sz = 0.f, sw = 0.f;
        #pragma unroll
        for (int i = 0; i < C / 4; ++i) {
            sx += xr[4*i+0]*xr[4*i+0]; sy += xr[4*i+1]*xr[4*i+1];
            sz += xr[4*i+2]*xr[4*i+2]; sw += xr[4*i+3]*xr[4*i+3];
        }
        rs = (sx + sy) + (sz + sw);
    }
    float v1 = INFINITY, v2 = INFINITY; int k1 = 0, k2 = 0;
    #pragma unroll 1
    for (int k0 = 0; k0 < KCODES; k0 += 4) {
        const float* c0 = cb + (size_t)k0 * C;
        float a0 = 0.f, a1 = 0.f, a2 = 0.f, a3 = 0.f;
        #pragma unroll
        for (int c = 0; c < C; ++c) {
            const float xc = xr[c];
            a0 = fmaf(xc, c0[c], a0);
            a1 = fmaf(xc, c0[C + c], a1);
            a2 = fmaf(xc, c0[2*C + c], a2);
            a3 = fmaf(xc, c0[3*C + c], a3);
        }
        const float d0 = (rs + s_cbsq[k0+0]) - 2.f * a0;
        const float d1 = (rs + s_cbsq[k0+1]) - 2.f * a1;
        const float d2 = (rs + s_cbsq[k0+2]) - 2.f * a2;
        const float d3 = (rs + s_cbsq[k0+3]) - 2.f * a3;
        #define UPDF(dv, kidx)                                               \
            if ((dv) < v1)      { v2 = v1; k2 = k1; v1 = (dv); k1 = (kidx); } \
            else if ((dv) < v2) { v2 = (dv); k2 = (kidx); }
        UPDF(d0, k0+0); UPDF(d1, k0+1); UPDF(d2, k0+2); UPDF(d3, k0+3);
        #undef UPDF
    }
    if (v2 - v1 < 0.125f) {
        const float* c1p = cb + (size_t)k1 * C;
        const float* c2p = cb + (size_t)k2 * C;
        double dot1 = 0.0, cq1 = 0.0, dot2 = 0.0, cq2 = 0.0;
        #pragma unroll 8
        for (int c = 0; c < C; ++c) {
            const double xc = (double)xr[c];
            const double cv1 = (double)c1p[c];
            const double cv2 = (double)c2p[c];
            dot1 += xc * cv1; cq1 += cv1 * cv1;
            dot2 += xc * cv2; cq2 += cv2 * cv2;
        }
        const double qa = cq1 - 2.0 * dot1;
        const double qb = cq2 - 2.0 * dot2;
        if (qb < qa || (qb == qa && k2 < k1)) { k1 = k2; v1 = (float)((double)rs + qb); }
    }
    {
        const float4* src = (const float4*)(cb + (size_t)k1 * C);
        float4* dst = (float4*)(out_codes + (size_t)row * C);
        #pragma unroll
        for (int i = 0; i < C / 4; ++i) dst[i] = src[i];
        out_fidx[row] = (float)k1;
        out_idx[row]  = (float)k1;
        out_dist[row] = v1;
    }
}

extern "C" void kernel_launch(void* const* d_in, const int* in_sizes, int n_in,
                              void* d_out, int out_size, void* d_ws, size_t ws_size,
                              hipStream_t stream) {
    const float* x  = (const float*)d_in[0];
    const float* cb = (const float*)d_in[1];
    const int rows = in_sizes[0] / C;   // 65536

    float* out       = (float*)d_out;
    float* out_codes = out;                          // rows*C
    float* out_fidx  = out + (size_t)rows * C;       // rows
    float* out_idx   = out_fidx + rows;              // rows
    float* out_dist  = out_idx + rows;               // rows

    // workspace: cbh (256KB) + cq (4KB)
    const size_t cbh_off = 0;
    const size_t cq_off  = (size_t)KCODES * C * sizeof(uint16_t);
    const size_t need    = cq_off + KCODES * sizeof(float);

    if (ws_size >= need) {
        uint16_t* cbh = (uint16_t*)((char*)d_ws + cbh_off);
        float*    cq  = (float*)((char*)d_ws + cq_off);

        cb_prep_kernel<<<(KCODES + TPB - 1) / TPB, TPB, 0, stream>>>(cb, cbh, cq);

        const int grid = (rows + ROWS_PB - 1) / ROWS_PB;   // 1024
        vq_mfma4_kernel<<<grid, TPB, 0, stream>>>(x, cb, cbh, cq,
                                                  out_codes, out_fidx, out_idx,
                                                  out_dist, rows);
    } else {
        const int rowblocks = (rows + TPB - 1) / TPB;
        vq_nearest_fallback<<<rowblocks, TPB, 0, stream>>>(x, cb, out_codes, out_fidx,
                                                           out_idx, out_dist, rows);
    }
}

// Round 7
// 202.448 us; speedup vs baseline: 1.4748x; 1.4748x over previous
//
#include <hip/hip_runtime.h>
#include <math.h>
#include <stdint.h>

#define C        128
#define KCODES   1024
#define TPB      256
#define ROWS_PB  64
#define NCHUNK   32                  // codes per partition per chunk
#define NCHUNKS  16                  // 512 / 32
#define BSTRIDE  272                 // padded LDS row stride (bytes)
#define PARTB    (NCHUNK * BSTRIDE)  // 8704
#define BUFB     (2 * PARTB)         // 17408 (two partitions)
#define EPS_TRIG 1.0f

typedef __attribute__((ext_vector_type(8))) short bf16x8_t;
typedef __attribute__((ext_vector_type(4))) float f32x4_t;
#define MFMA_BF16 __builtin_amdgcn_mfma_f32_16x16x32_bf16

static __device__ __forceinline__ uint32_t bf16_rne(float f) {
    uint32_t u = __float_as_uint(f);
    return (u + 0x7FFFu + ((u >> 16) & 1u)) >> 16;
}

// ---------------- prep: bf16(codebook) + ||c||^2 in one kernel ----------------
__global__ void cb_prep_kernel(const float* __restrict__ cb,
                               uint16_t* __restrict__ cbh,
                               float* __restrict__ cq) {
    int k = blockIdx.x * blockDim.x + threadIdx.x;
    if (k >= KCODES) return;
    const float4* cp = (const float4*)(cb + (size_t)k * C);
    uint32_t* hp = (uint32_t*)(cbh + (size_t)k * C);
    float sx = 0.f, sy = 0.f, sz = 0.f, sw = 0.f;
    #pragma unroll
    for (int i = 0; i < C / 4; ++i) {
        float4 v = cp[i];
        sx += v.x * v.x; sy += v.y * v.y;
        sz += v.z * v.z; sw += v.w * v.w;
        hp[2 * i]     = bf16_rne(v.x) | (bf16_rne(v.y) << 16);
        hp[2 * i + 1] = bf16_rne(v.z) | (bf16_rne(v.w) << 16);
    }
    cq[k] = (sx + sy) + (sz + sw);   // R1 arithmetic order
}

// All per-lane state is macro-generated NAMED SCALARS — no local arrays, no
// pointer escape, so nothing can be demoted to scratch (the R5/R6 failure).
#define SLOT8(OP) OP(0,0) OP(0,1) OP(0,2) OP(0,3) OP(1,0) OP(1,1) OP(1,2) OP(1,3)

__global__ __launch_bounds__(TPB, 3)
void vq_mfma5_kernel(const float* __restrict__ x,
                     const float* __restrict__ cb,
                     const uint16_t* __restrict__ cbh,
                     const float* __restrict__ cq,
                     float* __restrict__ out_codes,
                     float* __restrict__ out_fidx,
                     float* __restrict__ out_idx,
                     float* __restrict__ out_dist,
                     int rows)
{
    __shared__ __align__(16) uint8_t s_buf[2 * BUFB];   // 34816 B double-buffered
    __shared__ float s_cq[2][2][NCHUNK];                 // [buf][part][code]
    __shared__ float s_rv[2][ROWS_PB][3];
    __shared__ int   s_rk[2][ROWS_PB][3];
    __shared__ int   s_kf[ROWS_PB];

    const int t    = threadIdx.x;
    const int lane = t & 63;
    const int w    = t >> 6;
    const int part = w >> 1;        // code partition 0/1 (512 codes)
    const int rw   = w & 1;         // row-wave 0/1 (32 rows)
    const int ln   = lane & 15;
    const int quad = lane >> 4;
    const int rowblock = blockIdx.x * ROWS_PB;

    // ---- A fragments (bf16) straight from global, named scalars ----
    int rowg0 = rowblock + rw * 32 + ln;
    int rowg1 = rowg0 + 16;
    rowg0 = rowg0 < rows ? rowg0 : rows - 1;
    rowg1 = rowg1 < rows ? rowg1 : rows - 1;
    const float* xp0 = x + (size_t)rowg0 * C + quad * 8;
    const float* xp1 = x + (size_t)rowg1 * C + quad * 8;

    bf16x8_t ah00, ah01, ah02, ah03, ah10, ah11, ah12, ah13;
#define MKFRAG(dst, xp, kk) { \
    float4 v0 = *(const float4*)((xp) + (kk) * 32); \
    float4 v1 = *(const float4*)((xp) + (kk) * 32 + 4); \
    bf16x8_t hv; \
    hv[0] = (short)bf16_rne(v0.x); hv[1] = (short)bf16_rne(v0.y); \
    hv[2] = (short)bf16_rne(v0.z); hv[3] = (short)bf16_rne(v0.w); \
    hv[4] = (short)bf16_rne(v1.x); hv[5] = (short)bf16_rne(v1.y); \
    hv[6] = (short)bf16_rne(v1.z); hv[7] = (short)bf16_rne(v1.w); \
    dst = hv; }
    MKFRAG(ah00, xp0, 0) MKFRAG(ah01, xp0, 1) MKFRAG(ah02, xp0, 2) MKFRAG(ah03, xp0, 3)
    MKFRAG(ah10, xp1, 0) MKFRAG(ah11, xp1, 1) MKFRAG(ah12, xp1, 2) MKFRAG(ah13, xp1, 3)
#undef MKFRAG

    // ---- staging helpers (named regs ld0..ld3) ----
    uint4 ld0, ld1, ld2, ld3;
    float pcq = 0.f;
#define PREF(i, kb2) { \
    int u = t + (i) * TPB; \
    int pt = u >> 9, code = (u >> 4) & 31, gq = u & 15; \
    ld##i = ((const uint4*)cbh)[(((size_t)(pt * 512 + (kb2) + code)) << 4) + gq]; }
#define STOREB(i, dstbase) { \
    int u = t + (i) * TPB; \
    int pt = u >> 9, code = (u >> 4) & 31, gq = u & 15; \
    *(uint4*)((dstbase) + pt * PARTB + code * BSTRIDE + gq * 16) = ld##i; }

    // prologue: chunk 0 -> buffer 0
    PREF(0, 0) PREF(1, 0) PREF(2, 0) PREF(3, 0)
    if (t < 64) pcq = cq[(t >> 5) * 512 + (t & 31)];
    STOREB(0, s_buf) STOREB(1, s_buf) STOREB(2, s_buf) STOREB(3, s_buf)
    if (t < 64) s_cq[0][t >> 5][t & 31] = pcq;
    __syncthreads();

    // ---- top-3 state: named scalars ----
#define DECL(g,r) float q0_##g##r = INFINITY, q1_##g##r = INFINITY, q2_##g##r = INFINITY; \
                  int   i0_##g##r = 0x7fffffff, i1_##g##r = 0x7fffffff, i2_##g##r = 0x7fffffff;
    SLOT8(DECL)
#undef DECL

    #pragma unroll 1
    for (int chn = 0; chn < NCHUNKS; ++chn) {
        const int buf = chn & 1;
        if (chn + 1 < NCHUNKS) {
            const int kb2 = (chn + 1) * NCHUNK;
            PREF(0, kb2) PREF(1, kb2) PREF(2, kb2) PREF(3, kb2)
            if (t < 64) pcq = cq[(t >> 5) * 512 + kb2 + (t & 31)];
        }

        const uint8_t* bb = s_buf + buf * BUFB + part * PARTB + (size_t)ln * BSTRIDE + quad * 16;
        #pragma unroll
        for (int ct = 0; ct < 2; ++ct) {
            const uint8_t* bp = bb + (size_t)ct * 16 * BSTRIDE;
            f32x4_t acc0 = {0.f, 0.f, 0.f, 0.f};
            f32x4_t acc1 = {0.f, 0.f, 0.f, 0.f};
            {
                bf16x8_t bh0 = *(const bf16x8_t*)(bp);
                bf16x8_t bh1 = *(const bf16x8_t*)(bp + 64);
                bf16x8_t bh2 = *(const bf16x8_t*)(bp + 128);
                bf16x8_t bh3 = *(const bf16x8_t*)(bp + 192);
                acc0 = MFMA_BF16(ah00, bh0, acc0, 0, 0, 0);
                acc1 = MFMA_BF16(ah10, bh0, acc1, 0, 0, 0);
                acc0 = MFMA_BF16(ah01, bh1, acc0, 0, 0, 0);
                acc1 = MFMA_BF16(ah11, bh1, acc1, 0, 0, 0);
                acc0 = MFMA_BF16(ah02, bh2, acc0, 0, 0, 0);
                acc1 = MFMA_BF16(ah12, bh2, acc1, 0, 0, 0);
                acc0 = MFMA_BF16(ah03, bh3, acc0, 0, 0, 0);
                acc1 = MFMA_BF16(ah13, bh3, acc1, 0, 0, 0);
            }
            const float cqv = s_cq[buf][part][ct * 16 + ln];
            const int   kc  = part * 512 + chn * NCHUNK + ct * 16 + ln;
            // sorted top-3 insert; strict < keeps first occurrence (kc increasing)
#define UPD(g,r) { \
            float s_ = fmaf(-2.f, acc##g[r], cqv); \
            bool b0 = s_ < q0_##g##r; \
            bool b1 = s_ < q1_##g##r; \
            bool b2 = s_ < q2_##g##r; \
            q2_##g##r = b1 ? q1_##g##r : (b2 ? s_ : q2_##g##r); \
            i2_##g##r = b1 ? i1_##g##r : (b2 ? kc : i2_##g##r); \
            q1_##g##r = b0 ? q0_##g##r : (b1 ? s_ : q1_##g##r); \
            i1_##g##r = b0 ? i0_##g##r : (b1 ? kc : i1_##g##r); \
            q0_##g##r = b0 ? s_ : q0_##g##r; \
            i0_##g##r = b0 ? kc : i0_##g##r; }
            SLOT8(UPD)
#undef UPD
        }

        if (chn + 1 < NCHUNKS) {
            uint8_t* dst = s_buf + (1 - buf) * BUFB;
            STOREB(0, dst) STOREB(1, dst) STOREB(2, dst) STOREB(3, dst)
            if (t < 64) s_cq[1 - buf][t >> 5][t & 31] = pcq;
        }
        __syncthreads();
    }
#undef PREF
#undef STOREB

    // ---- butterfly top-3 merge across the 16 lanes of each col-group ----
    // lex insert of (v,k) into the named top-3 of slot (g,r)
#define INS(g,r,v,k) { \
    bool c0 = ((v) < q0_##g##r) || ((v) == q0_##g##r && (k) < i0_##g##r); \
    bool c1 = ((v) < q1_##g##r) || ((v) == q1_##g##r && (k) < i1_##g##r); \
    bool c2 = ((v) < q2_##g##r) || ((v) == q2_##g##r && (k) < i2_##g##r); \
    q2_##g##r = c1 ? q1_##g##r : (c2 ? (v) : q2_##g##r); \
    i2_##g##r = c1 ? i1_##g##r : (c2 ? (k) : i2_##g##r); \
    q1_##g##r = c0 ? q0_##g##r : (c1 ? (v) : q1_##g##r); \
    i1_##g##r = c0 ? i0_##g##r : (c1 ? (k) : i1_##g##r); \
    q0_##g##r = c0 ? (v) : q0_##g##r; \
    i0_##g##r = c0 ? (k) : i0_##g##r; }
    #pragma unroll
    for (int m_ = 1; m_ <= 8; m_ <<= 1) {
#define MRG(g,r) { \
        float ov0 = __shfl_xor(q0_##g##r, m_, 16); int ok0 = __shfl_xor(i0_##g##r, m_, 16); \
        float ov1 = __shfl_xor(q1_##g##r, m_, 16); int ok1 = __shfl_xor(i1_##g##r, m_, 16); \
        float ov2 = __shfl_xor(q2_##g##r, m_, 16); int ok2 = __shfl_xor(i2_##g##r, m_, 16); \
        INS(g,r,ov0,ok0) INS(g,r,ov1,ok1) INS(g,r,ov2,ok2) }
        SLOT8(MRG)
#undef MRG
    }
#undef INS

    if (ln == 0) {
#define WRT(g,r) { \
        int row_local = rw * 32 + g * 16 + quad * 4 + r; \
        s_rv[part][row_local][0] = q0_##g##r; s_rk[part][row_local][0] = i0_##g##r; \
        s_rv[part][row_local][1] = q1_##g##r; s_rk[part][row_local][1] = i1_##g##r; \
        s_rv[part][row_local][2] = q2_##g##r; s_rk[part][row_local][2] = i2_##g##r; }
        SLOT8(WRT)
#undef WRT
    }
    __syncthreads();

    // ---- per-row finalize: candidates read straight from LDS (no local arrays) ----
    if (t < ROWS_PB) {
        int rowg = rowblock + t;
        bool valid = rowg < rows;
        int rowc = valid ? rowg : rows - 1;

        // lex top-2 across the 6 LDS candidates
        float bv = INFINITY, sv = INFINITY;
        int   bk = 0x7fffffff, sk = 0x7fffffff;
        #pragma unroll
        for (int p = 0; p < 2; ++p)
            #pragma unroll
            for (int j = 0; j < 3; ++j) {
                float v = s_rv[p][t][j];
                int   k = s_rk[p][t][j];
                if (v < bv || (v == bv && k < bk)) { sv = bv; sk = bk; bv = v; bk = k; }
                else if (v < sv || (v == sv && k < sk)) { sv = v; sk = k; }
            }

        const float* xr = x + (size_t)rowc * C;
        // rs in R1 float4 order
        float sx = 0.f, sy = 0.f, sz = 0.f, sw = 0.f;
        {
            const float4* xpp = (const float4*)xr;
            #pragma unroll
            for (int i = 0; i < C / 4; ++i) {
                float4 v = xpp[i];
                sx += v.x * v.x; sy += v.y * v.y;
                sz += v.z * v.z; sw += v.w * v.w;
            }
        }
        const float rs = (sx + sy) + (sz + sw);

        int kfin = bk;
        float d;
        if (sv - bv >= EPS_TRIG) {
            // exact fp32 distance, R1 chain order
            const float* cp = cb + (size_t)kfin * C;
            float a = 0.f;
            #pragma unroll 16
            for (int cc = 0; cc < C; ++cc) a = fmaf(xr[cc], cp[cc], a);
            d = (rs + cq[kfin]) - 2.f * a;
        } else {
            // fp64 re-decide among all LDS candidates within the band
            double best = 1e300; int bestk = 0x7fffffff;
            #pragma unroll 1
            for (int p = 0; p < 2; ++p)
                #pragma unroll 1
                for (int j = 0; j < 3; ++j) {
                    float v = s_rv[p][t][j];
                    int   k = s_rk[p][t][j];
                    if (v - bv < EPS_TRIG) {
                        const float* cp = cb + (size_t)k * C;
                        double dot = 0.0, cqq = 0.0;
                        #pragma unroll 8
                        for (int cc = 0; cc < C; ++cc) {
                            double xv = (double)xr[cc], cvv = (double)cp[cc];
                            dot += xv * cvv; cqq += cvv * cvv;
                        }
                        double qd = cqq - 2.0 * dot;
                        if (qd < best || (qd == best && k < bestk)) { best = qd; bestk = k; }
                    }
                }
            kfin = bestk;
            d = (float)((double)rs + best);
        }

        if (valid) {
            out_fidx[rowg] = (float)kfin;
            out_idx[rowg]  = (float)kfin;
            out_dist[rowg] = d;
        }
        s_kf[t] = kfin;
    }
    __syncthreads();

    // ---- gather codes: 8 rows per iteration, 32 threads per row ----
    #pragma unroll 1
    for (int rr = 0; rr < ROWS_PB; rr += 8) {
        int r = rr + (t >> 5);
        int rowg2 = rowblock + r;
        if (rowg2 < rows) {
            const float4* src = (const float4*)(cb + (size_t)s_kf[r] * C);
            float4* dst = (float4*)(out_codes + (size_t)rowg2 * C);
            dst[t & 31] = src[t & 31];
        }
    }
}

// ---------------- fallback (R1 kernel, needs no workspace) ----------------
__global__ __launch_bounds__(TPB, 1)
void vq_nearest_fallback(const float* __restrict__ x,
                         const float* __restrict__ cb,
                         float* __restrict__ out_codes,
                         float* __restrict__ out_fidx,
                         float* __restrict__ out_idx,
                         float* __restrict__ out_dist,
                         int rows)
{
    __shared__ float s_cbsq[KCODES];
    const int t = threadIdx.x;
    for (int k = t; k < KCODES; k += TPB) {
        const float4* cp = (const float4*)(cb + (size_t)k * C);
        float sx = 0.f, sy = 0.f, sz = 0.f, sw = 0.f;
        #pragma unroll
        for (int i = 0; i < C / 4; ++i) {
            float4 v = cp[i];
            sx += v.x * v.x; sy += v.y * v.y; sz += v.z * v.z; sw += v.w * v.w;
        }
        s_cbsq[k] = (sx + sy) + (sz + sw);
    }
    __syncthreads();
    const int row = blockIdx.x * TPB + t;
    if (row >= rows) return;
    float xr[C];
    {
        const float4* xp = (const float4*)(x + (size_t)row * C);
        #pragma unroll
        for (int i = 0; i < C / 4; ++i) {
            float4 v = xp[i];
            xr[4*i+0] = v.x; xr[4*i+1] = v.y; xr[4*i+2] = v.z; xr[4*i+3] = v.w;
        }
    }
    float rs;
    {
        float sx = 0.f, sy = 0.f, sz = 0.f, sw = 0.f;
        #pragma unroll
        for (int i = 0; i < C / 4; ++i) {
            sx += xr[4*i+0]*xr[4*i+0]; sy += xr[4*i+1]*xr[4*i+1];
            sz += xr[4*i+2]*xr[4*i+2]; sw += xr[4*i+3]*xr[4*i+3];
        }
        rs = (sx + sy) + (sz + sw);
    }
    float v1 = INFINITY, v2 = INFINITY; int k1 = 0, k2 = 0;
    #pragma unroll 1
    for (int k0 = 0; k0 < KCODES; k0 += 4) {
        const float* c0 = cb + (size_t)k0 * C;
        float a0 = 0.f, a1 = 0.f, a2 = 0.f, a3 = 0.f;
        #pragma unroll
        for (int c = 0; c < C; ++c) {
            const float xc = xr[c];
            a0 = fmaf(xc, c0[c], a0);
            a1 = fmaf(xc, c0[C + c], a1);
            a2 = fmaf(xc, c0[2*C + c], a2);
            a3 = fmaf(xc, c0[3*C + c], a3);
        }
        const float d0 = (rs + s_cbsq[k0+0]) - 2.f * a0;
        const float d1 = (rs + s_cbsq[k0+1]) - 2.f * a1;
        const float d2 = (rs + s_cbsq[k0+2]) - 2.f * a2;
        const float d3 = (rs + s_cbsq[k0+3]) - 2.f * a3;
        #define UPDF(dv, kidx)                                               \
            if ((dv) < v1)      { v2 = v1; k2 = k1; v1 = (dv); k1 = (kidx); } \
            else if ((dv) < v2) { v2 = (dv); k2 = (kidx); }
        UPDF(d0, k0+0); UPDF(d1, k0+1); UPDF(d2, k0+2); UPDF(d3, k0+3);
        #undef UPDF
    }
    if (v2 - v1 < 0.125f) {
        const float* c1p = cb + (size_t)k1 * C;
        const float* c2p = cb + (size_t)k2 * C;
        double dot1 = 0.0, cq1 = 0.0, dot2 = 0.0, cq2 = 0.0;
        #pragma unroll 8
        for (int c = 0; c < C; ++c) {
            const double xc = (double)xr[c];
            const double cv1 = (double)c1p[c];
            const double cv2 = (double)c2p[c];
            dot1 += xc * cv1; cq1 += cv1 * cv1;
            dot2 += xc * cv2; cq2 += cv2 * cv2;
        }
        const double qa = cq1 - 2.0 * dot1;
        const double qb = cq2 - 2.0 * dot2;
        if (qb < qa || (qb == qa && k2 < k1)) { k1 = k2; v1 = (float)((double)rs + qb); }
    }
    {
        const float4* src = (const float4*)(cb + (size_t)k1 * C);
        float4* dst = (float4*)(out_codes + (size_t)row * C);
        #pragma unroll
        for (int i = 0; i < C / 4; ++i) dst[i] = src[i];
        out_fidx[row] = (float)k1;
        out_idx[row]  = (float)k1;
        out_dist[row] = v1;
    }
}

extern "C" void kernel_launch(void* const* d_in, const int* in_sizes, int n_in,
                              void* d_out, int out_size, void* d_ws, size_t ws_size,
                              hipStream_t stream) {
    const float* x  = (const float*)d_in[0];
    const float* cb = (const float*)d_in[1];
    const int rows = in_sizes[0] / C;   // 65536

    float* out       = (float*)d_out;
    float* out_codes = out;                          // rows*C
    float* out_fidx  = out + (size_t)rows * C;       // rows
    float* out_idx   = out_fidx + rows;              // rows
    float* out_dist  = out_idx + rows;               // rows

    // workspace: cbh (256KB) + cq (4KB)
    const size_t cbh_off = 0;
    const size_t cq_off  = (size_t)KCODES * C * sizeof(uint16_t);
    const size_t need    = cq_off + KCODES * sizeof(float);

    if (ws_size >= need) {
        uint16_t* cbh = (uint16_t*)((char*)d_ws + cbh_off);
        float*    cq  = (float*)((char*)d_ws + cq_off);

        cb_prep_kernel<<<(KCODES + TPB - 1) / TPB, TPB, 0, stream>>>(cb, cbh, cq);

        const int grid = (rows + ROWS_PB - 1) / ROWS_PB;   // 1024
        vq_mfma5_kernel<<<grid, TPB, 0, stream>>>(x, cb, cbh, cq,
                                                  out_codes, out_fidx, out_idx,
                                                  out_dist, rows);
    } else {
        const int rowblocks = (rows + TPB - 1) / TPB;
        vq_nearest_fallback<<<rowblocks, TPB, 0, stream>>>(x, cb, out_codes, out_fidx,
                                                           out_idx, out_dist, rows);
    }
}